// Round 6
// baseline (830.016 us; speedup 1.0000x reference)
//
#include <hip/hip_runtime.h>
#include <cstdint>

#define NT 512

// ws float offsets — weights transposed so each column's K-dim is contiguous
static constexpr int W0T_OFF = 0;        // w0T[n][o][m] : [8][325][32]  = 83200
static constexpr int W1T_OFF = 83200;    // w1T[k][o][m] : [50][52][26] = 67600
static constexpr int W2T_OFF = 150800;   // w2T[k][o][m] : [50][52][26] = 67600
static constexpr int CF_OFF  = 218400;   // gate coeffs float4 [3][1300] = 15600 floats
static constexpr int LG_OFF  = 234000;   // logits [B][10] f32

// ---------------------------------------------------------------------------
// Precompute: softmax conn weights (axis=1), stored transposed, and collapse
// the 16-gate bank to gate(A,B) = a + b*A + c*B + d*A*B.
// ---------------------------------------------------------------------------
__global__ void precompute_kernel(const float* __restrict__ c0,
                                  const float* __restrict__ w0,
                                  const float* __restrict__ c1,
                                  const float* __restrict__ w1,
                                  const float* __restrict__ c2,
                                  const float* __restrict__ w2,
                                  float* __restrict__ ws) {
  int id = blockIdx.x * blockDim.x + threadIdx.x;
  if (id < 2600) {  // layer-1 col (n,o): softmax over m=32 (stride 325 in src)
    int n = id / 325, o = id - n * 325;
    const float* src = c0 + n * (32 * 325) + o;
    float v[32]; float mx = -3.4e38f;
#pragma unroll
    for (int m = 0; m < 32; ++m) { v[m] = src[m * 325]; mx = fmaxf(mx, v[m]); }
    float ssum = 0.f;
#pragma unroll
    for (int m = 0; m < 32; ++m) { v[m] = __expf(v[m] - mx); ssum += v[m]; }
    float inv = 1.f / ssum;
    float* dst = ws + W0T_OFF + (n * 325 + o) * 32;
#pragma unroll
    for (int m = 0; m < 32; ++m) dst[m] = v[m] * inv;
    return;
  }
  id -= 2600;
  if (id < 5200) {  // layer-2/3 col (k,o): softmax over m=26
    const float* src0 = (id < 2600) ? c1 : c2;
    float* dst0 = ws + ((id < 2600) ? W1T_OFF : W2T_OFF);
    int col = (id < 2600) ? id : id - 2600;
    int k = col / 52, o = col - k * 52;
    const float* src = src0 + k * (26 * 52) + o;
    float v[26]; float mx = -3.4e38f;
#pragma unroll
    for (int m = 0; m < 26; ++m) { v[m] = src[m * 52]; mx = fmaxf(mx, v[m]); }
    float ssum = 0.f;
#pragma unroll
    for (int m = 0; m < 26; ++m) { v[m] = __expf(v[m] - mx); ssum += v[m]; }
    float inv = 1.f / ssum;
    float* dst = dst0 + (k * 52 + o) * 26;
#pragma unroll
    for (int m = 0; m < 26; ++m) dst[m] = v[m] * inv;
    return;
  }
  id -= 5200;
  if (id < 3900) {  // gate coefficients
    int layer = id / 1300, g = id - layer * 1300;
    const float* w = (layer == 0) ? w0 : ((layer == 1) ? w1 : w2);
    float v[16]; float mx = -3.4e38f;
#pragma unroll
    for (int k = 0; k < 16; ++k) { v[k] = w[k * 1300 + g]; mx = fmaxf(mx, v[k]); }
    float ssum = 0.f;
#pragma unroll
    for (int k = 0; k < 16; ++k) { v[k] = __expf(v[k] - mx); ssum += v[k]; }
    float inv = 1.f / ssum;
#pragma unroll
    for (int k = 0; k < 16; ++k) v[k] *= inv;
    float alpha = v[8] + v[9] + v[10] + v[11] + v[12] + v[13] + v[14] + v[15];
    float beta  = v[2] + v[3] + v[6] + v[7] - v[8] - v[9] - v[12] - v[13];
    float gamma = v[4] + v[5] + v[6] + v[7] - v[8] - v[9] - v[10] - v[11];
    float delta = v[1] - v[2] - v[4] - 2.f * v[6] - v[7] + v[8] + 2.f * v[9]
                + v[11] + v[13] - v[14];
    reinterpret_cast<float4*>(ws + CF_OFF)[id] =
        make_float4(alpha, beta, gamma, delta);
  }
}

__device__ __forceinline__ float gate4(float4 cv, float a0, float a1) {
  return fmaf(cv.w, a0 * a1, fmaf(cv.z, a1, fmaf(cv.y, a0, cv.x)));
}

// ---------------------------------------------------------------------------
// Chain kernel, 128-sample tiles, 2 samples per lane (rows lane, lane+64):
// each wave-uniform weight scalar feeds 2 FMAs -> s_load pressure per FMA
// halves vs round 5. 4 WGs per tile (class-aligned split {3,2,3,2} classes).
// Grid = 128*4 = 512 WGs -> 2 WGs/CU * 8 waves = 16 waves/CU; VGPR cap 128.
// ---------------------------------------------------------------------------
static constexpr int XB_STRIDE = 98;              // 96 cols + 2 pad
static constexpr int XB_ROWS   = 128;
static constexpr int XB_FLOATS = XB_ROWS * XB_STRIDE;  // 12544
static constexpr int LG_FLOATS = XB_ROWS * 3;          // max 3 classes per WG

__global__ __launch_bounds__(NT, 4) void chain_kernel(
    const float* __restrict__ x, const float* __restrict__ ws,
    float* __restrict__ lgout, int B) {
  extern __shared__ float smem[];
  float* xb  = smem;              // [128][98]
  float* lgb = smem + XB_FLOATS;  // [128][nlgc]
  const int tid = threadIdx.x;
  const int bid = blockIdx.x;
  const int tile = bid >> 2;
  const int half = (bid >> 1) & 1;
  const int sub = bid & 1;
  const int s0 = tile * XB_ROWS;

  const int base = half * 25 + sub * 15;  // first chain of this WG
  const int cnt_wg = sub ? 10 : 15;
  const int clsbase = half * 5 + sub * 3;
  const int nlgc = sub ? 2 : 3;
  const int bl0 = (52 * base) / 325;                          // first x-block
  const int nb = (52 * (base + cnt_wg) - 1) / 325 - bl0 + 1;  // 2 or 3

  // ---- stage needed x-blocks ([128][nb*32] <- coalesced float4), zero lgb ----
  {
    const float4* x4 = reinterpret_cast<const float4*>(x);
    const int rowq = nb * 8;  // float4s per row
    for (int idx = tid; idx < XB_ROWS * rowq; idx += NT) {
      int r = idx / rowq, c4 = idx - r * rowq;
      float4 v = make_float4(0.f, 0.f, 0.f, 0.f);
      if (s0 + r < B) v = x4[(size_t)(s0 + r) * 64 + bl0 * 8 + c4];
      float* d = &xb[r * XB_STRIDE + c4 * 4];
      d[0] = v.x; d[1] = v.y; d[2] = v.z; d[3] = v.w;
    }
    for (int i = tid; i < XB_ROWS * nlgc; i += NT) lgb[i] = 0.f;
  }
  __syncthreads();

  const int lane = tid & 63;
  const int wv = __builtin_amdgcn_readfirstlane(tid >> 6);  // 0..7
  const float* w0T = ws + W0T_OFF;
  const float* w1T = ws + W1T_OFF;
  const float* w2T = ws + W2T_OFF;
  const float4* cf = reinterpret_cast<const float4*>(ws + CF_OFF);
  const float* xrA = xb + lane * XB_STRIDE;          // sample s0+lane
  const float* xrB = xb + (lane + 64) * XB_STRIDE;   // sample s0+64+lane

  // chains per wave (critical path 2): sub0: 2*7+1; sub1: 2,2,1*6
  int cw, start;
  if (sub == 0) { cw = (wv < 7) ? 2 : 1; start = 2 * wv; }
  else          { cw = (wv < 2) ? 2 : 1; start = (wv < 2) ? 2 * wv : 2 + wv; }

#pragma unroll 1
  for (int ci = 0; ci < cw; ++ci) {
    const int K = base + start + ci;
    const int cs = 52 * K;
    const int nlo = cs / 325;
    const int nhi = (cs + 51) / 325;
    const int split = (nhi > nlo) ? (325 * nhi - cs) : 52;
    const int t1 = split >> 1;
    const int odd = split & 1;
    const float4* cfK = cf + 26 * K;
    const int offLo = (nlo - bl0) * 32;

    float hA[26], hB[26];

    // ---- layer 1, phase A (block nlo) ----
#pragma unroll
    for (int P = 0; P < 26; ++P) {
      if (P < t1) {
        const float* wp = w0T + (size_t)(nlo * 325 + (cs - 325 * nlo) + 2 * P) * 32;
        float a0A = 0.f, a1A = 0.f, a0B = 0.f, a1B = 0.f;
#pragma unroll
        for (int j = 0; j < 32; ++j) {
          float w0v = wp[j], w1v = wp[32 + j];
          float xA = xrA[offLo + j], xB = xrB[offLo + j];
          a0A = fmaf(xA, w0v, a0A); a1A = fmaf(xA, w1v, a1A);
          a0B = fmaf(xB, w0v, a0B); a1B = fmaf(xB, w1v, a1B);
        }
        float4 cv = cfK[P];
        hA[P] = gate4(cv, a0A, a1A);
        hB[P] = gate4(cv, a0B, a1B);
      }
    }
    // ---- straddle + phase B (block nhi) ----
    if (nhi > nlo) {
      const int offHi = (nhi - bl0) * 32;
      float gsA = 0.f, gsB = 0.f;
      if (odd) {  // pair t1: col in nlo x col in nhi
        const float* wp = w0T + (size_t)(nlo * 325 + (cs - 325 * nlo) + 2 * t1) * 32;
        const float* wq = w0T + (size_t)(nhi * 325) * 32;
        float a0A = 0.f, a0B = 0.f, a1A = 0.f, a1B = 0.f;
#pragma unroll
        for (int j = 0; j < 32; ++j) {
          float w0v = wp[j];
          a0A = fmaf(xrA[offLo + j], w0v, a0A);
          a0B = fmaf(xrB[offLo + j], w0v, a0B);
        }
#pragma unroll
        for (int j = 0; j < 32; ++j) {
          float w1v = wq[j];
          a1A = fmaf(xrA[offHi + j], w1v, a1A);
          a1B = fmaf(xrB[offHi + j], w1v, a1B);
        }
        float4 cv = cfK[t1];
        gsA = gate4(cv, a0A, a1A);
        gsB = gate4(cv, a0B, a1B);
      }
#pragma unroll
      for (int P = 0; P < 26; ++P) {
        if (P >= t1 + odd) {
          const float* wp = w0T + (size_t)(nhi * 325 + (cs - 325 * nhi) + 2 * P) * 32;
          float a0A = 0.f, a1A = 0.f, a0B = 0.f, a1B = 0.f;
#pragma unroll
          for (int j = 0; j < 32; ++j) {
            float w0v = wp[j], w1v = wp[32 + j];
            float xA = xrA[offHi + j], xB = xrB[offHi + j];
            a0A = fmaf(xA, w0v, a0A); a1A = fmaf(xA, w1v, a1A);
            a0B = fmaf(xB, w0v, a0B); a1B = fmaf(xB, w1v, a1B);
          }
          float4 cv = cfK[P];
          hA[P] = gate4(cv, a0A, a1A);
          hB[P] = gate4(cv, a0B, a1B);
        }
      }
      if (odd) {  // static-index select (avoid dynamic h[t1] write)
#pragma unroll
        for (int P = 0; P < 26; ++P)
          if (P == t1) { hA[P] = gsA; hB[P] = gsB; }
      }
    }

    // ---- layer 2 (register-resident, fully unrolled) ----
    float h2A[26], h2B[26];
    {
      const float* wb = w1T + (size_t)K * (52 * 26);
      const float4* cf1 = cf + 1300 + 26 * K;
#pragma unroll
      for (int q = 0; q < 26; ++q) {
        const float* wp = wb + q * 52;
        float a0A = 0.f, a1A = 0.f, a0B = 0.f, a1B = 0.f;
#pragma unroll
        for (int j = 0; j < 26; ++j) {
          float w0v = wp[j], w1v = wp[26 + j];
          a0A = fmaf(hA[j], w0v, a0A); a1A = fmaf(hA[j], w1v, a1A);
          a0B = fmaf(hB[j], w0v, a0B); a1B = fmaf(hB[j], w1v, a1B);
        }
        float4 cv = cf1[q];
        h2A[q] = gate4(cv, a0A, a1A);
        h2B[q] = gate4(cv, a0B, a1B);
      }
    }

    // ---- layer 3 + chain partial sums ----
    float psA = 0.f, psB = 0.f;
    {
      const float* wb = w2T + (size_t)K * (52 * 26);
      const float4* cf2 = cf + 2600 + 26 * K;
#pragma unroll 2
      for (int q = 0; q < 26; ++q) {
        const float* wp = wb + q * 52;
        float a0A = 0.f, a1A = 0.f, a0B = 0.f, a1B = 0.f;
#pragma unroll
        for (int j = 0; j < 26; ++j) {
          float w0v = wp[j], w1v = wp[26 + j];
          a0A = fmaf(h2A[j], w0v, a0A); a1A = fmaf(h2A[j], w1v, a1A);
          a0B = fmaf(h2B[j], w0v, a0B); a1B = fmaf(h2B[j], w1v, a1B);
        }
        float4 cv = cf2[q];
        psA += gate4(cv, a0A, a1A);
        psB += gate4(cv, a0B, a1B);
      }
    }
    const int lslot = K / 5 - clsbase;
    atomicAdd(&lgb[lane * nlgc + lslot], psA);
    atomicAdd(&lgb[(lane + 64) * nlgc + lslot], psB);
  }
  __syncthreads();

  // ---- write this WG's classes (disjoint across WGs, deterministic) ----
  for (int i = tid; i < XB_ROWS * nlgc; i += NT) {
    int s = i / nlgc, c = i - (i / nlgc) * nlgc;
    if (s0 + s < B) lgout[(size_t)(s0 + s) * 10 + clsbase + c] = lgb[i];
  }
}

// ---------------------------------------------------------------------------
// Finalize: per-sample 10-way softmax.
// ---------------------------------------------------------------------------
__global__ __launch_bounds__(256) void softmax_kernel(
    const float* __restrict__ lgin, float* __restrict__ out, int B) {
  int s = blockIdx.x * 256 + threadIdx.x;
  if (s >= B) return;
  float lg[10];
#pragma unroll
  for (int c = 0; c < 10; ++c) lg[c] = lgin[(size_t)s * 10 + c];
  float mx = lg[0];
#pragma unroll
  for (int c = 1; c < 10; ++c) mx = fmaxf(mx, lg[c]);
  float ssum = 0.f;
#pragma unroll
  for (int c = 0; c < 10; ++c) { lg[c] = __expf(lg[c] - mx); ssum += lg[c]; }
  float inv = 1.f / ssum;
  float* o = out + (size_t)s * 10;
#pragma unroll
  for (int c = 0; c < 10; ++c) o[c] = lg[c] * inv;
}

extern "C" void kernel_launch(void* const* d_in, const int* in_sizes, int n_in,
                              void* d_out, int out_size, void* d_ws, size_t ws_size,
                              hipStream_t stream) {
  const float* x  = (const float*)d_in[0];
  const float* c0 = (const float*)d_in[1];
  const float* w0 = (const float*)d_in[2];
  const float* c1 = (const float*)d_in[3];
  const float* w1 = (const float*)d_in[4];
  const float* c2 = (const float*)d_in[5];
  const float* w2 = (const float*)d_in[6];
  float* out = (float*)d_out;
  float* ws  = (float*)d_ws;
  const int B = in_sizes[0] / 256;

  precompute_kernel<<<46, 256, 0, stream>>>(c0, w0, c1, w1, c2, w2, ws);

  const size_t smem_bytes = (size_t)(XB_FLOATS + LG_FLOATS) * sizeof(float);
  hipFuncSetAttribute(reinterpret_cast<const void*>(chain_kernel),
                      hipFuncAttributeMaxDynamicSharedMemorySize, (int)smem_bytes);
  const int nblk = (B + XB_ROWS - 1) / XB_ROWS;
  chain_kernel<<<nblk * 4, NT, smem_bytes, stream>>>(x, ws, ws + LG_OFF, B);
  softmax_kernel<<<(B + 255) / 256, 256, 0, stream>>>(ws + LG_OFF, out, B);
}

// Round 7
// 542.139 us; speedup vs baseline: 1.5310x; 1.5310x over previous
//
#include <hip/hip_runtime.h>
#include <cstdint>

#define NT 512

// ws float offsets — weights transposed so each column's K-dim is contiguous
static constexpr int W0T_OFF = 0;        // w0T[n][o][m] : [8][325][32]  = 83200
static constexpr int W1T_OFF = 83200;    // w1T[k][o][m] : [50][52][26] = 67600
static constexpr int W2T_OFF = 150800;   // w2T[k][o][m] : [50][52][26] = 67600
static constexpr int CF_OFF  = 218400;   // gate coeffs float4 [3][1300] = 15600 floats
static constexpr int LG_OFF  = 234000;   // logits [B][10] f32

// ---------------------------------------------------------------------------
// Precompute: softmax conn weights (axis=1), stored transposed, and collapse
// the 16-gate bank to gate(A,B) = a + b*A + c*B + d*A*B.
// ---------------------------------------------------------------------------
__global__ void precompute_kernel(const float* __restrict__ c0,
                                  const float* __restrict__ w0,
                                  const float* __restrict__ c1,
                                  const float* __restrict__ w1,
                                  const float* __restrict__ c2,
                                  const float* __restrict__ w2,
                                  float* __restrict__ ws) {
  int id = blockIdx.x * blockDim.x + threadIdx.x;
  if (id < 2600) {  // layer-1 col (n,o): softmax over m=32 (stride 325 in src)
    int n = id / 325, o = id - n * 325;
    const float* src = c0 + n * (32 * 325) + o;
    float v[32]; float mx = -3.4e38f;
#pragma unroll
    for (int m = 0; m < 32; ++m) { v[m] = src[m * 325]; mx = fmaxf(mx, v[m]); }
    float ssum = 0.f;
#pragma unroll
    for (int m = 0; m < 32; ++m) { v[m] = __expf(v[m] - mx); ssum += v[m]; }
    float inv = 1.f / ssum;
    float* dst = ws + W0T_OFF + (n * 325 + o) * 32;
#pragma unroll
    for (int m = 0; m < 32; ++m) dst[m] = v[m] * inv;
    return;
  }
  id -= 2600;
  if (id < 5200) {  // layer-2/3 col (k,o): softmax over m=26
    const float* src0 = (id < 2600) ? c1 : c2;
    float* dst0 = ws + ((id < 2600) ? W1T_OFF : W2T_OFF);
    int col = (id < 2600) ? id : id - 2600;
    int k = col / 52, o = col - k * 52;
    const float* src = src0 + k * (26 * 52) + o;
    float v[26]; float mx = -3.4e38f;
#pragma unroll
    for (int m = 0; m < 26; ++m) { v[m] = src[m * 52]; mx = fmaxf(mx, v[m]); }
    float ssum = 0.f;
#pragma unroll
    for (int m = 0; m < 26; ++m) { v[m] = __expf(v[m] - mx); ssum += v[m]; }
    float inv = 1.f / ssum;
    float* dst = dst0 + (k * 52 + o) * 26;
#pragma unroll
    for (int m = 0; m < 26; ++m) dst[m] = v[m] * inv;
    return;
  }
  id -= 5200;
  if (id < 3900) {  // gate coefficients
    int layer = id / 1300, g = id - layer * 1300;
    const float* w = (layer == 0) ? w0 : ((layer == 1) ? w1 : w2);
    float v[16]; float mx = -3.4e38f;
#pragma unroll
    for (int k = 0; k < 16; ++k) { v[k] = w[k * 1300 + g]; mx = fmaxf(mx, v[k]); }
    float ssum = 0.f;
#pragma unroll
    for (int k = 0; k < 16; ++k) { v[k] = __expf(v[k] - mx); ssum += v[k]; }
    float inv = 1.f / ssum;
#pragma unroll
    for (int k = 0; k < 16; ++k) v[k] *= inv;
    float alpha = v[8] + v[9] + v[10] + v[11] + v[12] + v[13] + v[14] + v[15];
    float beta  = v[2] + v[3] + v[6] + v[7] - v[8] - v[9] - v[12] - v[13];
    float gamma = v[4] + v[5] + v[6] + v[7] - v[8] - v[9] - v[10] - v[11];
    float delta = v[1] - v[2] - v[4] - 2.f * v[6] - v[7] + v[8] + 2.f * v[9]
                + v[11] + v[13] - v[14];
    reinterpret_cast<float4*>(ws + CF_OFF)[id] =
        make_float4(alpha, beta, gamma, delta);
  }
}

__device__ __forceinline__ float gate4(float4 cv, float a0, float a1) {
  return fmaf(cv.w, a0 * a1, fmaf(cv.z, a1, fmaf(cv.y, a0, cv.x)));
}
__device__ __forceinline__ float4 vload4(const float* p) {
  return *reinterpret_cast<const float4*>(p);
}
// component select; c is compile-time constant after unrolling
__device__ __forceinline__ float f4c(const float4& v, int c) {
  return c == 0 ? v.x : (c == 1 ? v.y : (c == 2 ? v.z : v.w));
}

// ---------------------------------------------------------------------------
// Chain kernel (round-5 structure: 64-sample tiles, sample = lane, 4 WGs per
// tile class-aligned {3,2,3,2}; grid = 1024 WGs).
// KEY CHANGE: weight/coeff base pointers are laundered through an opaque
// VGPR zero so loads go through VMEM (global_load_dwordx4, vmcnt-pipelined)
// instead of SMEM (s_load, which only supports lgkmcnt(0) full drains and
// therefore cannot be software-pipelined). All lanes read the same line ->
// coalesced broadcast, no extra traffic.
// ---------------------------------------------------------------------------
static constexpr int XB_STRIDE = 98;              // 96 cols + 2 pad
static constexpr int XB_FLOATS = 64 * XB_STRIDE;  // 6272
static constexpr int LG_FLOATS = 64 * 3;          // max 3 classes per WG

__global__ __launch_bounds__(NT, 4) void chain_kernel(
    const float* __restrict__ x, const float* __restrict__ ws,
    float* __restrict__ lgout, int B) {
  extern __shared__ float smem[];
  float* xb  = smem;              // [64][98]
  float* lgb = smem + XB_FLOATS;  // [64][nlgc]
  const int tid = threadIdx.x;
  const int bid = blockIdx.x;
  const int tile = bid >> 2;
  const int half = (bid >> 1) & 1;
  const int sub = bid & 1;
  const int s0 = tile * 64;

  const int base = half * 25 + sub * 15;  // first chain of this WG
  const int cnt_wg = sub ? 10 : 15;
  const int clsbase = half * 5 + sub * 3;
  const int nlgc = sub ? 2 : 3;
  const int bl0 = (52 * base) / 325;                          // first x-block
  const int nb = (52 * (base + cnt_wg) - 1) / 325 - bl0 + 1;  // 2 or 3

  // ---- stage needed x-blocks ([64][nb*32] <- coalesced float4), zero lgb ----
  {
    const float4* x4 = reinterpret_cast<const float4*>(x);
    const int rowq = nb * 8;  // float4s per row
    for (int idx = tid; idx < 64 * rowq; idx += NT) {
      int r = idx / rowq, c4 = idx - r * rowq;
      float4 v = make_float4(0.f, 0.f, 0.f, 0.f);
      if (s0 + r < B) v = x4[(size_t)(s0 + r) * 64 + bl0 * 8 + c4];
      float* d = &xb[r * XB_STRIDE + c4 * 4];
      d[0] = v.x; d[1] = v.y; d[2] = v.z; d[3] = v.w;
    }
    for (int i = tid; i < 64 * nlgc; i += NT) lgb[i] = 0.f;
  }
  __syncthreads();

  const int lane = tid & 63;
  const int wv = __builtin_amdgcn_readfirstlane(tid >> 6);  // 0..7

  // opaque VGPR zero: forces VMEM (pipelinable) instead of SMEM for weights
  int vzero;
  asm("v_mov_b32 %0, 0" : "=v"(vzero));
  const float* w0T = ws + W0T_OFF + vzero;
  const float* w1T = ws + W1T_OFF + vzero;
  const float* w2T = ws + W2T_OFF + vzero;
  const float4* cf = reinterpret_cast<const float4*>(ws + CF_OFF) + vzero;

  const float* xrow = xb + lane * XB_STRIDE;

  // chains per wave (critical path 2): sub0: 2*7+1; sub1: 2,2,1*6
  int cw, start;
  if (sub == 0) { cw = (wv < 7) ? 2 : 1; start = 2 * wv; }
  else          { cw = (wv < 2) ? 2 : 1; start = (wv < 2) ? 2 * wv : 2 + wv; }

#pragma unroll 1
  for (int ci = 0; ci < cw; ++ci) {
    const int K = base + start + ci;
    const int cs = 52 * K;
    const int nlo = cs / 325;
    const int nhi = (cs + 51) / 325;
    const int split = (nhi > nlo) ? (325 * nhi - cs) : 52;
    const int t1 = split >> 1;
    const int odd = split & 1;
    const float4* cfK = cf + 26 * K;

    float h[26];
    float inp[32];
#pragma unroll
    for (int j = 0; j < 32; ++j) inp[j] = xrow[(nlo - bl0) * 32 + j];

    // ---- layer 1, phase A (block nlo) ----
#pragma unroll
    for (int P = 0; P < 26; ++P) {
      if (P < t1) {
        const float* wp = w0T + (size_t)(nlo * 325 + (cs - 325 * nlo) + 2 * P) * 32;
        float a0 = 0.f, a1 = 0.f;
#pragma unroll
        for (int hf = 0; hf < 2; ++hf) {
          float4 wa[4], wb4[4];
#pragma unroll
          for (int t = 0; t < 4; ++t) {
            wa[t]  = vload4(wp + hf * 16 + 4 * t);
            wb4[t] = vload4(wp + 32 + hf * 16 + 4 * t);
          }
#pragma unroll
          for (int j = 0; j < 16; ++j) {
            float xv = inp[hf * 16 + j];
            a0 = fmaf(xv, f4c(wa[j >> 2], j & 3), a0);
            a1 = fmaf(xv, f4c(wb4[j >> 2], j & 3), a1);
          }
        }
        h[P] = gate4(cfK[P], a0, a1);
      }
    }
    // ---- straddle + phase B (block nhi) ----
    if (nhi > nlo) {
      float a0s = 0.f, a1s = 0.f, gs = 0.f;
      if (odd) {
        const float* wp = w0T + (size_t)(nlo * 325 + (cs - 325 * nlo) + 2 * t1) * 32;
#pragma unroll
        for (int j = 0; j < 32; ++j) a0s = fmaf(inp[j], wp[j], a0s);
      }
#pragma unroll
      for (int j = 0; j < 32; ++j) inp[j] = xrow[(nhi - bl0) * 32 + j];
      if (odd) {
        const float* wq = w0T + (size_t)(nhi * 325) * 32;
#pragma unroll
        for (int j = 0; j < 32; ++j) a1s = fmaf(inp[j], wq[j], a1s);
        gs = gate4(cfK[t1], a0s, a1s);
      }
#pragma unroll
      for (int P = 0; P < 26; ++P) {
        if (P >= t1 + odd) {
          const float* wp = w0T + (size_t)(nhi * 325 + (cs - 325 * nhi) + 2 * P) * 32;
          float a0 = 0.f, a1 = 0.f;
#pragma unroll
          for (int hf = 0; hf < 2; ++hf) {
            float4 wa[4], wb4[4];
#pragma unroll
            for (int t = 0; t < 4; ++t) {
              wa[t]  = vload4(wp + hf * 16 + 4 * t);
              wb4[t] = vload4(wp + 32 + hf * 16 + 4 * t);
            }
#pragma unroll
            for (int j = 0; j < 16; ++j) {
              float xv = inp[hf * 16 + j];
              a0 = fmaf(xv, f4c(wa[j >> 2], j & 3), a0);
              a1 = fmaf(xv, f4c(wb4[j >> 2], j & 3), a1);
            }
          }
          h[P] = gate4(cfK[P], a0, a1);
        }
      }
      if (odd) {  // static-index select (avoid dynamic h[t1] write)
#pragma unroll
        for (int P = 0; P < 26; ++P)
          if (P == t1) h[P] = gs;
      }
    }

    // ---- layer 2 (register-resident, fully unrolled) ----
    float h2[26];
    {
      const float* wb = w1T + (size_t)K * (52 * 26);
      const float4* cf1 = cf + 1300 + 26 * K;
#pragma unroll
      for (int q = 0; q < 26; ++q) {
        const float* wp = wb + q * 52;   // 52 floats = cols (2q,2q+1), 16B aligned
        float4 wq[13];
#pragma unroll
        for (int t = 0; t < 13; ++t) wq[t] = vload4(wp + 4 * t);
        float a0 = 0.f, a1 = 0.f;
#pragma unroll
        for (int j = 0; j < 26; ++j) {
          a0 = fmaf(h[j], f4c(wq[j >> 2], j & 3), a0);
          int jj = 26 + j;
          a1 = fmaf(h[j], f4c(wq[jj >> 2], jj & 3), a1);
        }
        h2[q] = gate4(cf1[q], a0, a1);
      }
    }

    // ---- layer 3 + chain partial sum ----
    float psum = 0.f;
    {
      const float* wb = w2T + (size_t)K * (52 * 26);
      const float4* cf2 = cf + 2600 + 26 * K;
#pragma unroll 2
      for (int q = 0; q < 26; ++q) {
        const float* wp = wb + q * 52;
        float4 wq[13];
#pragma unroll
        for (int t = 0; t < 13; ++t) wq[t] = vload4(wp + 4 * t);
        float a0 = 0.f, a1 = 0.f;
#pragma unroll
        for (int j = 0; j < 26; ++j) {
          a0 = fmaf(h2[j], f4c(wq[j >> 2], j & 3), a0);
          int jj = 26 + j;
          a1 = fmaf(h2[j], f4c(wq[jj >> 2], jj & 3), a1);
        }
        psum += gate4(cf2[q], a0, a1);
      }
    }
    atomicAdd(&lgb[lane * nlgc + (K / 5 - clsbase)], psum);
  }
  __syncthreads();

  // ---- write this WG's classes (disjoint across WGs, deterministic) ----
  for (int i = tid; i < 64 * nlgc; i += NT) {
    int s = i / nlgc, c = i - (i / nlgc) * nlgc;
    if (s0 + s < B) lgout[(size_t)(s0 + s) * 10 + clsbase + c] = lgb[i];
  }
}

// ---------------------------------------------------------------------------
// Finalize: per-sample 10-way softmax.
// ---------------------------------------------------------------------------
__global__ __launch_bounds__(256) void softmax_kernel(
    const float* __restrict__ lgin, float* __restrict__ out, int B) {
  int s = blockIdx.x * 256 + threadIdx.x;
  if (s >= B) return;
  float lg[10];
#pragma unroll
  for (int c = 0; c < 10; ++c) lg[c] = lgin[(size_t)s * 10 + c];
  float mx = lg[0];
#pragma unroll
  for (int c = 1; c < 10; ++c) mx = fmaxf(mx, lg[c]);
  float ssum = 0.f;
#pragma unroll
  for (int c = 0; c < 10; ++c) { lg[c] = __expf(lg[c] - mx); ssum += lg[c]; }
  float inv = 1.f / ssum;
  float* o = out + (size_t)s * 10;
#pragma unroll
  for (int c = 0; c < 10; ++c) o[c] = lg[c] * inv;
}

extern "C" void kernel_launch(void* const* d_in, const int* in_sizes, int n_in,
                              void* d_out, int out_size, void* d_ws, size_t ws_size,
                              hipStream_t stream) {
  const float* x  = (const float*)d_in[0];
  const float* c0 = (const float*)d_in[1];
  const float* w0 = (const float*)d_in[2];
  const float* c1 = (const float*)d_in[3];
  const float* w1 = (const float*)d_in[4];
  const float* c2 = (const float*)d_in[5];
  const float* w2 = (const float*)d_in[6];
  float* out = (float*)d_out;
  float* ws  = (float*)d_ws;
  const int B = in_sizes[0] / 256;

  precompute_kernel<<<46, 256, 0, stream>>>(c0, w0, c1, w1, c2, w2, ws);

  const size_t smem_bytes = (size_t)(XB_FLOATS + LG_FLOATS) * sizeof(float);
  hipFuncSetAttribute(reinterpret_cast<const void*>(chain_kernel),
                      hipFuncAttributeMaxDynamicSharedMemorySize, (int)smem_bytes);
  const int nblk = (B + 63) / 64;
  chain_kernel<<<nblk * 4, NT, smem_bytes, stream>>>(x, ws, ws + LG_OFF, B);
  softmax_kernel<<<(B + 255) / 256, 256, 0, stream>>>(ws + LG_OFF, out, B);
}